// Round 2
// baseline (299.533 us; speedup 1.0000x reference)
//
#include <hip/hip_runtime.h>

// HeatMap: out[b,q,t,h,w,f] = relu( sum_g ( dot_c(dec[b,q,t,g,:], enc[b,t,h,w,g,:]) ) * W[g,f] + bias[f] )
// b=4, q=16 (of 20), t=8, h=w=16, g=8, c=64, f=512. Output 256 MB fp32 -> write-BW bound.
//
// One wave per (b,q,t,h); loop over w (16 positions). Per-lane f-slice = lane*8..lane*8+7.
// Score partials per lane cover (g = lane>>3, c = (lane&7)*8 .. +7) -> per-lane dec/enc offset = lane*8.

__device__ __forceinline__ float bcast_lane(float v, int srcLane) {
    return __uint_as_float(__builtin_amdgcn_readlane(__float_as_uint(v), srcLane));
}

__global__ __launch_bounds__(256) void heatmap_kernel(
    const float* __restrict__ dec,   // (4,20,8,512)
    const float* __restrict__ enc,   // (4,8,16,16,512)
    const float* __restrict__ W,     // (8,512)
    const float* __restrict__ bias,  // (512,)
    float* __restrict__ out)         // (4,16,8,16,16,512)
{
    const int tid  = threadIdx.x;
    const int lane = tid & 63;
    const int wid  = blockIdx.x * 4 + (tid >> 6);   // 0..8191 = (b,q,t,h)

    const int h = wid & 15;
    const int t = (wid >> 4) & 7;
    const int q = (wid >> 7) & 15;
    const int b = wid >> 11;

    const int f0 = lane * 8;

    // Per-lane W fragment: W[g][f0..f0+7] (64 VGPRs), bias fragment (8 VGPRs). Loaded once per wave.
    float4 Wr0[8], Wr1[8];
#pragma unroll
    for (int g = 0; g < 8; ++g) {
        Wr0[g] = *reinterpret_cast<const float4*>(W + g * 512 + f0);
        Wr1[g] = *reinterpret_cast<const float4*>(W + g * 512 + f0 + 4);
    }
    const float4 bi0 = *reinterpret_cast<const float4*>(bias + f0);
    const float4 bi1 = *reinterpret_cast<const float4*>(bias + f0 + 4);

    // Per-lane dec fragment (8 floats), fixed per wave. Note q-dim of btn_dec is 20, we use 0..15.
    const float* decp = dec + (size_t)(((b * 20 + q) * 8 + t)) * 512 + f0;
    const float4 d0 = *reinterpret_cast<const float4*>(decp);
    const float4 d1 = *reinterpret_cast<const float4*>(decp + 4);

    const size_t ebase = (size_t)((b * 8 + t) * 256 + h * 16) * 512; // enc row for w=0
    const size_t obase = (size_t)wid * 16 * 512;                     // out row for w=0

#pragma unroll 4
    for (int w = 0; w < 16; ++w) {
        const float* ep = enc + ebase + (size_t)w * 512 + f0;
        const float4 e0 = *reinterpret_cast<const float4*>(ep);
        const float4 e1 = *reinterpret_cast<const float4*>(ep + 4);

        // Per-lane partial of score[g = lane>>3] over its 8 c's.
        float p = d0.x * e0.x + d0.y * e0.y + d0.z * e0.z + d0.w * e0.w
                + d1.x * e1.x + d1.y * e1.y + d1.z * e1.z + d1.w * e1.w;

        // Reduce within each 8-lane group (DPP, no LDS).
        p += __shfl_xor(p, 1);
        p += __shfl_xor(p, 2);
        p += __shfl_xor(p, 4);

        // Broadcast the 8 scores to all lanes as SGPRs.
        float s[8];
#pragma unroll
        for (int g = 0; g < 8; ++g)
            s[g] = bcast_lane(p, g * 8);

        // Project to f-space: acc[j] = bias[f0+j] + sum_g s[g]*W[g][f0+j], then relu.
        float4 a0 = bi0, a1 = bi1;
#pragma unroll
        for (int g = 0; g < 8; ++g) {
            a0.x += s[g] * Wr0[g].x;  a0.y += s[g] * Wr0[g].y;
            a0.z += s[g] * Wr0[g].z;  a0.w += s[g] * Wr0[g].w;
            a1.x += s[g] * Wr1[g].x;  a1.y += s[g] * Wr1[g].y;
            a1.z += s[g] * Wr1[g].z;  a1.w += s[g] * Wr1[g].w;
        }
        a0.x = fmaxf(a0.x, 0.f); a0.y = fmaxf(a0.y, 0.f);
        a0.z = fmaxf(a0.z, 0.f); a0.w = fmaxf(a0.w, 0.f);
        a1.x = fmaxf(a1.x, 0.f); a1.y = fmaxf(a1.y, 0.f);
        a1.z = fmaxf(a1.z, 0.f); a1.w = fmaxf(a1.w, 0.f);

        float* op = out + obase + (size_t)w * 512 + f0;
        *reinterpret_cast<float4*>(op)     = a0;
        *reinterpret_cast<float4*>(op + 4) = a1;
    }
}

extern "C" void kernel_launch(void* const* d_in, const int* in_sizes, int n_in,
                              void* d_out, int out_size, void* d_ws, size_t ws_size,
                              hipStream_t stream) {
    const float* dec  = (const float*)d_in[0];
    const float* enc  = (const float*)d_in[1];
    const float* W    = (const float*)d_in[2];
    const float* bias = (const float*)d_in[3];
    float* out = (float*)d_out;

    // 8192 waves = 4*16*8*16 (b,q,t,h); 4 waves per block.
    heatmap_kernel<<<2048, 256, 0, stream>>>(dec, enc, W, bias, out);
}